// Round 1
// baseline (207.923 us; speedup 1.0000x reference)
//
#include <hip/hip_runtime.h>
#include <hip/hip_bf16.h>

#define D 1024      // in_features
#define E 64        // num experts
#define TPB 256     // threads per block (4 waves)
#define TOKS 64     // tokens per block (16 per wave)
#define KC 64       // k per staged W chunk (2 MFMA k-steps)
#define BROW 72     // padded bf16 row length for staged W (64 + 8)

typedef __attribute__((ext_vector_type(8))) short bf16x8;
typedef __attribute__((ext_vector_type(4))) float f32x4;
typedef __attribute__((ext_vector_type(4))) unsigned short u16x4;

__device__ __forceinline__ unsigned short bf16_rne(float f) {
    unsigned u = __builtin_bit_cast(unsigned, f);
    u += 0x7fffu + ((u >> 16) & 1u);
    return (unsigned short)(u >> 16);
}
__device__ __forceinline__ float bf16_to_f(unsigned short h) {
    unsigned u = ((unsigned)h) << 16;
    return __builtin_bit_cast(float, u);
}
__device__ __forceinline__ void split_hi_lo(float v, unsigned short& h, unsigned short& l) {
    h = bf16_rne(v);
    l = bf16_rne(v - bf16_to_f(h));
}

__global__ __launch_bounds__(TPB) void router_kernel(
        const float* __restrict__ x, const float* __restrict__ W,
        const float* __restrict__ bias, float* __restrict__ out, int T) {
    // LDS: staged W chunk (hi/lo bf16, padded rows) unioned with epilogue logits
    __shared__ __align__(16) union SM {
        struct { unsigned short hi[E][BROW]; unsigned short lo[E][BROW]; } b;
        float ls[TOKS][E + 1];
    } sm;
    __shared__ float sbias[E];

    const int tid  = threadIdx.x;
    const int lane = tid & 63;
    const int wid  = tid >> 6;     // wave id 0..3 -> 16-token strip
    const int n    = lane & 15;    // MFMA m/n index within tile
    const int q    = lane >> 4;    // MFMA quad -> k offset q*8
    const int t0   = blockIdx.x * TOKS;

    if (tid < E) sbias[tid] = bias[tid];

    f32x4 acc[4];
#pragma unroll
    for (int i = 0; i < 4; ++i) acc[i] = (f32x4){0.f, 0.f, 0.f, 0.f};

    // A source: this lane reads 8 consecutive fp32 per k-step, MFMA lane order
    const float* arow = x + (size_t)(t0 + wid * 16 + n) * D + q * 8;

    // --- prefetch chunk 0 (W staging regs + A regs) ---
    f32x4 wreg[4];
#pragma unroll
    for (int r = 0; r < 4; ++r) {
        int idx = r * TPB + tid;           // 0..1023
        int e = idx >> 4, part = idx & 15; // row, 16B-slot within 64-k chunk
        wreg[r] = *(const f32x4*)(W + e * D + part * 4);
    }
    f32x4 areg[4];
#pragma unroll
    for (int s = 0; s < 2; ++s) {
        areg[2 * s]     = *(const f32x4*)(arow + s * 32);
        areg[2 * s + 1] = *(const f32x4*)(arow + s * 32 + 4);
    }

    for (int kc = 0; kc < D; kc += KC) {
        // ---- write staged W chunk (split to hi/lo bf16) into LDS ----
#pragma unroll
        for (int r = 0; r < 4; ++r) {
            int idx = r * TPB + tid;
            int e = idx >> 4, part = idx & 15;
            unsigned short h[4], l[4];
#pragma unroll
            for (int j = 0; j < 4; ++j) split_hi_lo(wreg[r][j], h[j], l[j]);
            *(u16x4*)&sm.b.hi[e][part * 4] = (u16x4){h[0], h[1], h[2], h[3]};
            *(u16x4*)&sm.b.lo[e][part * 4] = (u16x4){l[0], l[1], l[2], l[3]};
        }
        __syncthreads();

        // ---- prefetch next chunk (branchless wrap; last iter reloads chunk 0) ----
        int kn = (kc + KC) & (D - 1);
#pragma unroll
        for (int r = 0; r < 4; ++r) {
            int idx = r * TPB + tid;
            int e = idx >> 4, part = idx & 15;
            wreg[r] = *(const f32x4*)(W + e * D + kn + part * 4);
        }
        f32x4 anext[4];
#pragma unroll
        for (int s = 0; s < 2; ++s) {
            anext[2 * s]     = *(const f32x4*)(arow + kn + s * 32);
            anext[2 * s + 1] = *(const f32x4*)(arow + kn + s * 32 + 4);
        }

        // ---- compute: 2 MFMA k-steps per chunk ----
#pragma unroll
        for (int s = 0; s < 2; ++s) {
            unsigned short ah[8], al[8];
#pragma unroll
            for (int j = 0; j < 4; ++j) {
                split_hi_lo(areg[2 * s][j],     ah[j],     al[j]);
                split_hi_lo(areg[2 * s + 1][j], ah[4 + j], al[4 + j]);
            }
            bf16x8 ahv, alv;
#pragma unroll
            for (int j = 0; j < 8; ++j) { ahv[j] = (short)ah[j]; alv[j] = (short)al[j]; }
#pragma unroll
            for (int nt = 0; nt < 4; ++nt) {
                const bf16x8 bh = *(const bf16x8*)&sm.b.hi[nt * 16 + n][s * 32 + q * 8];
                const bf16x8 bl = *(const bf16x8*)&sm.b.lo[nt * 16 + n][s * 32 + q * 8];
                acc[nt] = __builtin_amdgcn_mfma_f32_16x16x32_bf16(ahv, bh, acc[nt], 0, 0, 0);
                acc[nt] = __builtin_amdgcn_mfma_f32_16x16x32_bf16(alv, bh, acc[nt], 0, 0, 0);
                acc[nt] = __builtin_amdgcn_mfma_f32_16x16x32_bf16(ahv, bl, acc[nt], 0, 0, 0);
            }
        }
#pragma unroll
        for (int i = 0; i < 4; ++i) areg[i] = anext[i];
        __syncthreads();
    }

    // ---- epilogue: logits (+bias) to LDS, then per-token softmax + top-2 ----
#pragma unroll
    for (int nt = 0; nt < 4; ++nt) {
        int col = nt * 16 + n;
        float bv = sbias[col];
#pragma unroll
        for (int r = 0; r < 4; ++r) {
            // C/D layout: col = lane&15, row = (lane>>4)*4 + reg
            sm.ls[wid * 16 + q * 4 + r][col] = acc[nt][r] + bv;
        }
    }
    __syncthreads();

    if (tid < TOKS) {
        float m1 = -3.4e38f, m2 = -3.4e38f;
        int i1 = 0, i2 = 0;
        for (int e = 0; e < E; ++e) {
            float v = sm.ls[tid][e];
            if (v > m1) { m2 = m1; i2 = i1; m1 = v; i1 = e; }
            else if (v > m2) { m2 = v; i2 = e; }
        }
        float Z = 0.f;
        for (int e = 0; e < E; ++e) Z += __expf(sm.ls[tid][e] - m1);
        float inv = 1.f / Z;
        int gt = t0 + tid;
        out[(size_t)gt * 2]     = inv;                 // exp(m1-m1)/Z
        out[(size_t)gt * 2 + 1] = __expf(m2 - m1) * inv;
        float* oi = out + (size_t)T * 2;
        oi[(size_t)gt * 2]     = (float)i1;            // indices stored as float values
        oi[(size_t)gt * 2 + 1] = (float)i2;
    }
}

extern "C" void kernel_launch(void* const* d_in, const int* in_sizes, int n_in,
                              void* d_out, int out_size, void* d_ws, size_t ws_size,
                              hipStream_t stream) {
    const float* x = (const float*)d_in[0];
    const float* W = (const float*)d_in[1];
    const float* b = (const float*)d_in[2];
    float* out = (float*)d_out;
    int T = in_sizes[0] / D;          // 32768 tokens
    int blocks = T / TOKS;            // 512
    hipLaunchKernelGGL(router_kernel, dim3(blocks), dim3(TPB), 0, stream,
                       x, W, b, out, T);
}